// Round 20
// baseline (183.171 us; speedup 1.0000x reference)
//
#include <hip/hip_runtime.h>
#include <math.h>

namespace {

constexpr int NF   = 256;    // n_feature / tokens
constexpr int NFP  = NF + 32;// padded (2-deep quad prefetch overrun, zeroed)
constexpr int EH   = 128;    // embedder hidden
constexpr int E    = 64;     // embedded dim
constexpr int H    = 64;     // lstm size
constexpr int SHD  = 256;    // shared hidden
constexpr int SD   = 128;    // shared dim
constexpr int NA   = 257;    // n_action
constexpr int NSHUF = 4;

__device__ __forceinline__ float fsig(float x) {
  return 1.f / (1.f + __expf(-x));
}
__device__ __forceinline__ float ftanh(float x) {
  return 1.f - 2.f / (__expf(2.f * x) + 1.f);
}

// Pre-kernel: transpose Wp2 [128][257] -> Wp2T [257][128] and
// We2 [128][64] -> We2T [64][128] into workspace (L2-resident, ~3us).
// Removes the last scalar-load blocks: adv (512 dword -> 128 float4/row)
// and attended (128 dword -> 32 float4 per attention iteration).
__global__ __launch_bounds__(256) void transpose_wk(
    const float* __restrict__ Wp2, const float* __restrict__ We2,
    float* __restrict__ Wp2T, float* __restrict__ We2T)
{
  const int tid = blockIdx.x * 256 + threadIdx.x;
  if (tid < NA * SD) {
    const int c = tid / SD, k = tid - c * SD;
    Wp2T[tid] = Wp2[k * NA + c];
  } else if (tid < NA * SD + E * EH) {
    const int t2 = tid - NA * SD;
    const int c = t2 / EH, k = t2 - c * EH;
    We2T[t2] = We2[k * E + c];
  }
}

// ONE WAVE PER ROW, ZERO BARRIERS (r14+). Quad-stream token loops with
// 2-DEEP meta pipeline (meta j+2 || rows j+1 || compute j) so the LDS-meta
// -> global-row serial chain (~320cy) pipelines. Vectorized weight streams
// (r19) + transposed Wp2/We2 for adv/attended (this round).
// Factored attention (r11+ verified): logits = h.(We2 qt) (const cancels);
// attended = (sum w h)@We2 + be2; h recomputed from We1 on the fly.
__global__ __launch_bounds__(64)
void seqnet(
    const float* __restrict__ state, const int* __restrict__ acquired,
    const float* __restrict__ We1, const float* __restrict__ be1,
    const float* __restrict__ We2, const float* __restrict__ be2,
    const float* __restrict__ Wih, const float* __restrict__ Whh,
    const float* __restrict__ bih, const float* __restrict__ bhh,
    const float* __restrict__ Ws1, const float* __restrict__ bs1,
    const float* __restrict__ Ws2, const float* __restrict__ bs2,
    const float* __restrict__ Wp1, const float* __restrict__ bp1,
    const float* __restrict__ Wp2T, const float* __restrict__ bp2,
    const float* __restrict__ Wv1, const float* __restrict__ bv1,
    const float* __restrict__ Wv2, const float* __restrict__ bv2,
    const float* __restrict__ We2T,
    float* __restrict__ out)
{
  const int row = blockIdx.x;
  const int l   = threadIdx.x;    // 0..63 (one wave)
  const int g   = l >> 4;         // token group 0..3
  const int sub = l & 15;         // k-slice owner within group
  const int kbase = sub * 8;      // owns k = kbase..kbase+7

  __shared__ int   id_s[NFP];
  __shared__ __align__(16) float val_s[NFP];
  __shared__ __align__(16) float w_s[NFP];
  __shared__ __align__(16) float rv_s[EH];
  __shared__ __align__(16) float u_s[EH];
  __shared__ __align__(16) float enc_s[EH];   // att[0:64] | qt[64:128]
  __shared__ __align__(16) float gates_s[256];
  __shared__ __align__(16) float t1_s[SHD];
  __shared__ __align__(16) float sh_s[SD];
  __shared__ __align__(16) float a1_s[SD];
  __shared__ __align__(16) float v1_s[SD];

  // ---------------- phase 0: closed-form "argsort" (wave-local) -----------
  const int* __restrict__ arow = acquired + row * NF;
  #pragma unroll
  for (int j = 0; j < 4; ++j) { id_s[l + 64 * j] = 0; val_s[l + 64 * j] = 0.f; }
  if (l < 32) { id_s[NF + l] = 0; val_s[NF + l] = 0.f; w_s[NF + l] = 0.f; }
  int aiv[4];
  unsigned long long m0, m1, m2, m3;
  aiv[0] = (arow[l]       != 0); m0 = __ballot(aiv[0]);
  aiv[1] = (arow[64 + l]  != 0); m1 = __ballot(aiv[1]);
  aiv[2] = (arow[128 + l] != 0); m2 = __ballot(aiv[2]);
  aiv[3] = (arow[192 + l] != 0); m3 = __ballot(aiv[3]);
  const int pc0 = __popcll(m0), pc1 = __popcll(m1);
  const int pc2 = __popcll(m2), pc3 = __popcll(m3);
  const int L = pc0 + pc1 + pc2 + pc3;
  {  // rank = # acquired with index > tok (descending stable order)
    const int suf1 = pc1 + pc2 + pc3, suf2 = pc2 + pc3, suf3 = pc3;
    if (aiv[0]) { const int r = (int)__popcll((m0 >> l) >> 1) + suf1;
      id_s[r] = l + 1;       val_s[r] = state[row * NF + l]; }
    if (aiv[1]) { const int r = (int)__popcll((m1 >> l) >> 1) + suf2;
      id_s[r] = 64 + l + 1;  val_s[r] = state[row * NF + 64 + l]; }
    if (aiv[2]) { const int r = (int)__popcll((m2 >> l) >> 1) + suf3;
      id_s[r] = 128 + l + 1; val_s[r] = state[row * NF + 128 + l]; }
    if (aiv[3]) { const int r = (int)__popcll((m3 >> l) >> 1);
      id_s[r] = 192 + l + 1; val_s[r] = state[row * NF + 192 + l]; }
  }

  float ct_r = 0.f;

  // hoisted per-lane h-recompute constants for k-slice [kbase, kbase+8)
  const float4 z0 = *(const float4*)(We1 + kbase);        // row 0 (val weight)
  const float4 z1 = *(const float4*)(We1 + kbase + 4);
  const float4 c0 = *(const float4*)(be1 + kbase);
  const float4 c1 = *(const float4*)(be1 + kbase + 4);

  if (L > 0) {
    const float invL = 1.f / (float)L;
    // group g owns tokens {4i+g}; quad = tokens 16j+g+{0,4,8,12}
    const int ntok  = (L > g) ? ((L - g + 3) >> 2) : 0;
    const int nquad = (ntok + 3) >> 2;
    for (int it = 0; it < NSHUF; ++it) {
      if (it == 0) {
        // qt == 0 -> uniform softmax over first L tokens
        #pragma unroll
        for (int j = 0; j < 4; ++j) w_s[l + 64 * j] = (l + 64 * j < L) ? invL : 0.f;
      } else {
        // rv = We2 @ qt : lane computes rv[l], rv[64+l]; qt from LDS float4
        {
          const float4* __restrict__ r0 = (const float4*)(We2 + l * E);
          const float4* __restrict__ r1 = (const float4*)(We2 + (64 + l) * E);
          float a0 = 0.f, a1 = 0.f, b0 = 0.f, b1 = 0.f;
          #pragma unroll
          for (int j = 0; j < 16; j += 2) {
            const float4 x0 = r0[j], x1 = r1[j];
            const float4 q4 = *(const float4*)(enc_s + 64 + 4 * j);
            a0 = fmaf(x0.x, q4.x, a0); a1 = fmaf(x1.x, q4.x, a1);
            a0 = fmaf(x0.y, q4.y, a0); a1 = fmaf(x1.y, q4.y, a1);
            a0 = fmaf(x0.z, q4.z, a0); a1 = fmaf(x1.z, q4.z, a1);
            a0 = fmaf(x0.w, q4.w, a0); a1 = fmaf(x1.w, q4.w, a1);
            const float4 y0 = r0[j + 1], y1 = r1[j + 1];
            const float4 q5 = *(const float4*)(enc_s + 64 + 4 * j + 4);
            b0 = fmaf(y0.x, q5.x, b0); b1 = fmaf(y1.x, q5.x, b1);
            b0 = fmaf(y0.y, q5.y, b0); b1 = fmaf(y1.y, q5.y, b1);
            b0 = fmaf(y0.z, q5.z, b0); b1 = fmaf(y1.z, q5.z, b1);
            b0 = fmaf(y0.w, q5.w, b0); b1 = fmaf(y1.w, q5.w, b1);
          }
          rv_s[l] = a0 + b0; rv_s[64 + l] = a1 + b1;
        }
        const float4 ra = *(const float4*)(rv_s + kbase);
        const float4 rb = *(const float4*)(rv_s + kbase + 4);
        // logits: quad-stream, 2-deep meta pipeline (meta j+2 || rows j+1)
        int idp[4]; float vcur[4], vnx[4];
        #pragma unroll
        for (int s = 0; s < 4; ++s) {
          vcur[s] = val_s[g + 4 * s];
          idp[s]  = id_s[16 + g + 4 * s]; vnx[s] = val_s[16 + g + 4 * s];
        }
        float4 gA[4], gB[4];
        #pragma unroll
        for (int s = 0; s < 4; ++s) {
          const int id0 = id_s[g + 4 * s];
          gA[s] = *(const float4*)(We1 + id0 * EH + kbase);
          gB[s] = *(const float4*)(We1 + id0 * EH + kbase + 4);
        }
        for (int j = 0; j < nquad; ++j) {
          const int b2 = 16 * (j + 2) + g;
          int idn[4]; float vn[4];
          #pragma unroll
          for (int s = 0; s < 4; ++s) { idn[s] = id_s[b2 + 4 * s]; vn[s] = val_s[b2 + 4 * s]; }
          float4 gA2[4], gB2[4];
          #pragma unroll
          for (int s = 0; s < 4; ++s) {
            gA2[s] = *(const float4*)(We1 + idp[s] * EH + kbase);
            gB2[s] = *(const float4*)(We1 + idp[s] * EH + kbase + 4);
          }
          float p[4];
          #pragma unroll
          for (int s = 0; s < 4; ++s) {
            float h, pp;
            h = fmaxf(fmaf(vcur[s], z0.x, gA[s].x) + c0.x, 0.f); pp = h * ra.x;
            h = fmaxf(fmaf(vcur[s], z0.y, gA[s].y) + c0.y, 0.f); pp = fmaf(h, ra.y, pp);
            h = fmaxf(fmaf(vcur[s], z0.z, gA[s].z) + c0.z, 0.f); pp = fmaf(h, ra.z, pp);
            h = fmaxf(fmaf(vcur[s], z0.w, gA[s].w) + c0.w, 0.f); pp = fmaf(h, ra.w, pp);
            h = fmaxf(fmaf(vcur[s], z1.x, gB[s].x) + c1.x, 0.f); pp = fmaf(h, rb.x, pp);
            h = fmaxf(fmaf(vcur[s], z1.y, gB[s].y) + c1.y, 0.f); pp = fmaf(h, rb.y, pp);
            h = fmaxf(fmaf(vcur[s], z1.z, gB[s].z) + c1.z, 0.f); pp = fmaf(h, rb.z, pp);
            h = fmaxf(fmaf(vcur[s], z1.w, gB[s].w) + c1.w, 0.f); pp = fmaf(h, rb.w, pp);
            p[s] = pp;
          }
          #pragma unroll
          for (int s = 0; s < 4; ++s) {
            p[s] += __shfl_xor(p[s], 1); p[s] += __shfl_xor(p[s], 2);
            p[s] += __shfl_xor(p[s], 4); p[s] += __shfl_xor(p[s], 8);
          }
          if (sub == 0) {
            const int bcur = 16 * j + g;
            w_s[bcur]      = p[0]; w_s[bcur + 4]  = p[1];
            w_s[bcur + 8]  = p[2]; w_s[bcur + 12] = p[3];
          }
          #pragma unroll
          for (int s = 0; s < 4; ++s) {
            vcur[s] = vnx[s]; vnx[s] = vn[s]; idp[s] = idn[s];
            gA[s] = gA2[s]; gB[s] = gB2[s];
          }
        }
        // softmax over w_s[0..L), 4 tokens per lane
        float x0 = (l < L)       ? w_s[l]       : -1e30f;
        float x1 = (64 + l < L)  ? w_s[64 + l]  : -1e30f;
        float x2 = (128 + l < L) ? w_s[128 + l] : -1e30f;
        float x3 = (192 + l < L) ? w_s[192 + l] : -1e30f;
        float mx = fmaxf(fmaxf(x0, x1), fmaxf(x2, x3));
        #pragma unroll
        for (int d = 32; d > 0; d >>= 1) mx = fmaxf(mx, __shfl_xor(mx, d));
        const float e0 = (l < L)       ? __expf(x0 - mx) : 0.f;
        const float e1 = (64 + l < L)  ? __expf(x1 - mx) : 0.f;
        const float e2 = (128 + l < L) ? __expf(x2 - mx) : 0.f;
        const float e3 = (192 + l < L) ? __expf(x3 - mx) : 0.f;
        float s = (e0 + e1) + (e2 + e3);
        #pragma unroll
        for (int d = 32; d > 0; d >>= 1) s += __shfl_xor(s, d);
        const float inv = 1.f / s;
        w_s[l]       = e0 * inv;
        w_s[64 + l]  = e1 * inv;
        w_s[128 + l] = e2 * inv;
        w_s[192 + l] = e3 * inv;
      }

      // u[k] = sum_tok w*h : quad-stream, 2-deep meta pipeline
      float4 ua{0, 0, 0, 0}, ub{0, 0, 0, 0};
      {
        int idp[4]; float vcur[4], wcur[4], vnx[4], wnx[4];
        #pragma unroll
        for (int s = 0; s < 4; ++s) {
          vcur[s] = val_s[g + 4 * s]; wcur[s] = w_s[g + 4 * s];
          idp[s]  = id_s[16 + g + 4 * s];
          vnx[s]  = val_s[16 + g + 4 * s]; wnx[s] = w_s[16 + g + 4 * s];
        }
        float4 gA[4], gB[4];
        #pragma unroll
        for (int s = 0; s < 4; ++s) {
          const int id0 = id_s[g + 4 * s];
          gA[s] = *(const float4*)(We1 + id0 * EH + kbase);
          gB[s] = *(const float4*)(We1 + id0 * EH + kbase + 4);
        }
        for (int j = 0; j < nquad; ++j) {
          const int b2 = 16 * (j + 2) + g;
          int idn[4]; float vn[4], wn[4];
          #pragma unroll
          for (int s = 0; s < 4; ++s) {
            idn[s] = id_s[b2 + 4 * s]; vn[s] = val_s[b2 + 4 * s]; wn[s] = w_s[b2 + 4 * s];
          }
          float4 gA2[4], gB2[4];
          #pragma unroll
          for (int s = 0; s < 4; ++s) {
            gA2[s] = *(const float4*)(We1 + idp[s] * EH + kbase);
            gB2[s] = *(const float4*)(We1 + idp[s] * EH + kbase + 4);
          }
          #pragma unroll
          for (int s = 0; s < 4; ++s) {
            const float vt = vcur[s], wt = wcur[s];
            float h;
            h = fmaxf(fmaf(vt, z0.x, gA[s].x) + c0.x, 0.f); ua.x = fmaf(wt, h, ua.x);
            h = fmaxf(fmaf(vt, z0.y, gA[s].y) + c0.y, 0.f); ua.y = fmaf(wt, h, ua.y);
            h = fmaxf(fmaf(vt, z0.z, gA[s].z) + c0.z, 0.f); ua.z = fmaf(wt, h, ua.z);
            h = fmaxf(fmaf(vt, z0.w, gA[s].w) + c0.w, 0.f); ua.w = fmaf(wt, h, ua.w);
            h = fmaxf(fmaf(vt, z1.x, gB[s].x) + c1.x, 0.f); ub.x = fmaf(wt, h, ub.x);
            h = fmaxf(fmaf(vt, z1.y, gB[s].y) + c1.y, 0.f); ub.y = fmaf(wt, h, ub.y);
            h = fmaxf(fmaf(vt, z1.z, gB[s].z) + c1.z, 0.f); ub.z = fmaf(wt, h, ub.z);
            h = fmaxf(fmaf(vt, z1.w, gB[s].w) + c1.w, 0.f); ub.w = fmaf(wt, h, ub.w);
          }
          #pragma unroll
          for (int s = 0; s < 4; ++s) {
            vcur[s] = vnx[s]; wcur[s] = wnx[s];
            vnx[s] = vn[s];   wnx[s] = wn[s];   idp[s] = idn[s];
            gA[s] = gA2[s];   gB[s] = gB2[s];
          }
        }
      }
      #pragma unroll
      for (int d = 16; d <= 32; d <<= 1) {   // cross-group: same sub = same k
        ua.x += __shfl_xor(ua.x, d); ua.y += __shfl_xor(ua.y, d);
        ua.z += __shfl_xor(ua.z, d); ua.w += __shfl_xor(ua.w, d);
        ub.x += __shfl_xor(ub.x, d); ub.y += __shfl_xor(ub.y, d);
        ub.z += __shfl_xor(ub.z, d); ub.w += __shfl_xor(ub.w, d);
      }
      if (l < 16) {
        *(float4*)(u_s + l * 8)     = ua;
        *(float4*)(u_s + l * 8 + 4) = ub;
      }

      // attended[l] = dot(We2T row l, u) + be2[l]   (float4 row stream)
      {
        const float4* __restrict__ wt = (const float4*)(We2T + l * EH);
        const float4* __restrict__ uv = (const float4*)u_s;
        float a0 = 0.f, a1 = 0.f, a2 = 0.f, a3 = 0.f;
        #pragma unroll 8
        for (int kk = 0; kk < 32; ++kk) {
          const float4 w = wt[kk];
          const float4 u = uv[kk];
          a0 = fmaf(u.x, w.x, a0); a1 = fmaf(u.y, w.y, a1);
          a2 = fmaf(u.z, w.z, a2); a3 = fmaf(u.w, w.w, a3);
        }
        enc_s[l] = (a0 + a1) + (a2 + a3) + be2[l];
      }

      // gates: lane owns cols 4l..4l+3 -> float4 weight loads; LDS roundtrip
      {
        float4 acc0{0, 0, 0, 0}, acc1{0, 0, 0, 0};
        #pragma unroll 2
        for (int e = 0; e < E; e += 2) {
          const float av0 = enc_s[e], av1 = enc_s[e + 1];
          const float4 w0 = *(const float4*)(Wih + (e)     * 256 + 4 * l);
          const float4 w1 = *(const float4*)(Wih + (e + 1) * 256 + 4 * l);
          acc0.x = fmaf(av0, w0.x, acc0.x); acc0.y = fmaf(av0, w0.y, acc0.y);
          acc0.z = fmaf(av0, w0.z, acc0.z); acc0.w = fmaf(av0, w0.w, acc0.w);
          acc1.x = fmaf(av1, w1.x, acc1.x); acc1.y = fmaf(av1, w1.y, acc1.y);
          acc1.z = fmaf(av1, w1.z, acc1.z); acc1.w = fmaf(av1, w1.w, acc1.w);
        }
        if (it > 0) {
          #pragma unroll 2
          for (int e = 0; e < E; e += 2) {
            const float qv0 = enc_s[64 + e], qv1 = enc_s[64 + e + 1];
            const float4 w0 = *(const float4*)(Whh + (e)     * 256 + 4 * l);
            const float4 w1 = *(const float4*)(Whh + (e + 1) * 256 + 4 * l);
            acc0.x = fmaf(qv0, w0.x, acc0.x); acc0.y = fmaf(qv0, w0.y, acc0.y);
            acc0.z = fmaf(qv0, w0.z, acc0.z); acc0.w = fmaf(qv0, w0.w, acc0.w);
            acc1.x = fmaf(qv1, w1.x, acc1.x); acc1.y = fmaf(qv1, w1.y, acc1.y);
            acc1.z = fmaf(qv1, w1.z, acc1.z); acc1.w = fmaf(qv1, w1.w, acc1.w);
          }
        }
        const float4 bi = *(const float4*)(bih + 4 * l);
        const float4 bh = *(const float4*)(bhh + 4 * l);
        float4 gacc;
        gacc.x = acc0.x + acc1.x + bi.x + bh.x;
        gacc.y = acc0.y + acc1.y + bi.y + bh.y;
        gacc.z = acc0.z + acc1.z + bi.z + bh.z;
        gacc.w = acc0.w + acc1.w + bi.w + bh.w;
        *(float4*)(gates_s + 4 * l) = gacc;
        // per-cell gates back from LDS (same-wave RAW, ordered)
        const float gi = gates_s[l];
        const float gf = gates_s[64 + l];
        const float gg = gates_s[128 + l];
        const float go = gates_s[192 + l];
        ct_r = fsig(gf) * ct_r + fsig(gi) * ftanh(gg);
        enc_s[64 + l] = fsig(go) * ftanh(ct_r);   // qt in LDS (wave-local)
      }
    }
  } else {
    enc_s[l] = 0.f; enc_s[64 + l] = 0.f;   // reference zeroes encoded
  }

  // ---------------- phase 3: DuelingNet (vectorized weight streams) -------
  {  // t1 cols 4l..4l+3 via float4; dual-parity accumulators
    float4 acc0{0, 0, 0, 0}, acc1{0, 0, 0, 0};
    #pragma unroll 2
    for (int k = 0; k < EH; k += 2) {
      const float e0 = enc_s[k], e1 = enc_s[k + 1];
      const float4 w0 = *(const float4*)(Ws1 + (k)     * SHD + 4 * l);
      const float4 w1 = *(const float4*)(Ws1 + (k + 1) * SHD + 4 * l);
      acc0.x = fmaf(e0, w0.x, acc0.x); acc0.y = fmaf(e0, w0.y, acc0.y);
      acc0.z = fmaf(e0, w0.z, acc0.z); acc0.w = fmaf(e0, w0.w, acc0.w);
      acc1.x = fmaf(e1, w1.x, acc1.x); acc1.y = fmaf(e1, w1.y, acc1.y);
      acc1.z = fmaf(e1, w1.z, acc1.z); acc1.w = fmaf(e1, w1.w, acc1.w);
    }
    const float4 b4 = *(const float4*)(bs1 + 4 * l);
    t1_s[4 * l]     = fmaxf(acc0.x + acc1.x + b4.x, 0.f);
    t1_s[4 * l + 1] = fmaxf(acc0.y + acc1.y + b4.y, 0.f);
    t1_s[4 * l + 2] = fmaxf(acc0.z + acc1.z + b4.z, 0.f);
    t1_s[4 * l + 3] = fmaxf(acc0.w + acc1.w + b4.w, 0.f);
  }
  {  // sh cols 2l, 2l+1 via float2
    float2 acc0{0, 0}, acc1{0, 0};
    #pragma unroll 2
    for (int k = 0; k < SHD; k += 2) {
      const float t0 = t1_s[k], t1v = t1_s[k + 1];
      const float2 w0 = *(const float2*)(Ws2 + (k)     * SD + 2 * l);
      const float2 w1 = *(const float2*)(Ws2 + (k + 1) * SD + 2 * l);
      acc0.x = fmaf(t0, w0.x, acc0.x); acc0.y = fmaf(t0, w0.y, acc0.y);
      acc1.x = fmaf(t1v, w1.x, acc1.x); acc1.y = fmaf(t1v, w1.y, acc1.y);
    }
    sh_s[2 * l]     = fmaxf(acc0.x + acc1.x + bs2[2 * l],     0.f);
    sh_s[2 * l + 1] = fmaxf(acc0.y + acc1.y + bs2[2 * l + 1], 0.f);
  }
  {  // a1, v1 cols 2l, 2l+1 via float2 (two independent streams)
    float2 pa{0, 0}, qa{0, 0};
    #pragma unroll 2
    for (int k = 0; k < SD; ++k) {
      const float sv = sh_s[k];
      const float2 wp = *(const float2*)(Wp1 + k * SD + 2 * l);
      const float2 wv = *(const float2*)(Wv1 + k * SD + 2 * l);
      pa.x = fmaf(sv, wp.x, pa.x); pa.y = fmaf(sv, wp.y, pa.y);
      qa.x = fmaf(sv, wv.x, qa.x); qa.y = fmaf(sv, wv.y, qa.y);
    }
    a1_s[2 * l]     = fmaxf(pa.x + bp1[2 * l],     0.f);
    a1_s[2 * l + 1] = fmaxf(pa.y + bp1[2 * l + 1], 0.f);
    v1_s[2 * l]     = fmaxf(qa.x + bv1[2 * l],     0.f);
    v1_s[2 * l + 1] = fmaxf(qa.y + bv1[2 * l + 1], 0.f);
  }
  // adv cols l+64j via Wp2T rows (float4 streams)
  float a0, a1, a2, a3;
  {
    float acc[4];
    const float4* __restrict__ av = (const float4*)a1_s;
    #pragma unroll
    for (int jj = 0; jj < 4; ++jj) {
      const float4* __restrict__ wr = (const float4*)(Wp2T + (l + 64 * jj) * SD);
      float b0 = 0.f, b1 = 0.f, b2 = 0.f, b3 = 0.f;
      #pragma unroll 8
      for (int kk = 0; kk < 32; ++kk) {
        const float4 w = wr[kk];
        const float4 a = av[kk];
        b0 = fmaf(a.x, w.x, b0); b1 = fmaf(a.y, w.y, b1);
        b2 = fmaf(a.z, w.z, b2); b3 = fmaf(a.w, w.w, b3);
      }
      acc[jj] = (b0 + b1) + (b2 + b3);
    }
    a0 = acc[0] + bp2[l];
    a1 = acc[1] + bp2[64 + l];
    a2 = acc[2] + bp2[128 + l];
    a3 = acc[3] + bp2[192 + l];
  }
  // adv col 256: distributed dot over Wp2T row 256 (float2) + butterfly
  const float2 wc = *(const float2*)(Wp2T + 256 * SD + 2 * l);
  float c4 = fmaf(a1_s[2 * l], wc.x, a1_s[2 * l + 1] * wc.y);
  #pragma unroll
  for (int d = 32; d > 0; d >>= 1) c4 += __shfl_xor(c4, d);
  const float adv4 = c4 + bp2[256];
  // v scalar
  float vv = fmaf(v1_s[l], Wv2[l], v1_s[64 + l] * Wv2[64 + l]);
  #pragma unroll
  for (int d = 32; d > 0; d >>= 1) vv += __shfl_xor(vv, d);
  const float v = vv + bv2[0];
  // mean over 257 cols
  float ss = (a0 + a1) + (a2 + a3);
  #pragma unroll
  for (int d = 32; d > 0; d >>= 1) ss += __shfl_xor(ss, d);
  const float mean = (ss + adv4) * (1.f / (float)NA);

  const float base = v - mean;
  float* __restrict__ orow = out + row * NA;
  orow[l]       = base + a0;
  orow[64 + l]  = base + a1;
  orow[128 + l] = base + a2;
  orow[192 + l] = base + a3;
  if (l == 0) orow[256] = base + adv4;
}

}  // namespace

extern "C" void kernel_launch(void* const* d_in, const int* in_sizes, int n_in,
                              void* d_out, int out_size, void* d_ws, size_t ws_size,
                              hipStream_t stream) {
  const float* state    = (const float*)d_in[0];
  const int*   acquired = (const int*)d_in[1];
  const float* We1 = (const float*)d_in[2];
  const float* be1 = (const float*)d_in[3];
  const float* We2 = (const float*)d_in[4];
  const float* be2 = (const float*)d_in[5];
  const float* Wih = (const float*)d_in[6];
  const float* Whh = (const float*)d_in[7];
  const float* bih = (const float*)d_in[8];
  const float* bhh = (const float*)d_in[9];
  const float* Ws1 = (const float*)d_in[10];
  const float* bs1 = (const float*)d_in[11];
  const float* Ws2 = (const float*)d_in[12];
  const float* bs2 = (const float*)d_in[13];
  const float* Wp1 = (const float*)d_in[14];
  const float* bp1 = (const float*)d_in[15];
  const float* Wp2 = (const float*)d_in[16];
  const float* bp2 = (const float*)d_in[17];
  const float* Wv1 = (const float*)d_in[18];
  const float* bv1 = (const float*)d_in[19];
  const float* Wv2 = (const float*)d_in[20];
  const float* bv2 = (const float*)d_in[21];
  float* out = (float*)d_out;

  float* Wp2T = (float*)d_ws;                 // [257][128]
  float* We2T = Wp2T + NA * SD;               // [64][128]

  const int nT = NA * SD + E * EH;
  hipLaunchKernelGGL(transpose_wk, dim3((nT + 255) / 256), dim3(256), 0, stream,
                     Wp2, We2, Wp2T, We2T);

  const int Bn = in_sizes[0] / NF;   // 2048 rows; one 64-thread wave per row
  hipLaunchKernelGGL(seqnet, dim3(Bn), dim3(64), 0, stream,
                     state, acquired, We1, be1, We2, be2, Wih, Whh, bih, bhh,
                     Ws1, bs1, Ws2, bs2, Wp1, bp1, Wp2T, bp2, Wv1, bv1, Wv2, bv2,
                     We2T, out);
}

// Round 21
// 140.368 us; speedup vs baseline: 1.3049x; 1.3049x over previous
//
#include <hip/hip_runtime.h>
#include <math.h>

namespace {

constexpr int NF   = 256;    // n_feature / tokens
constexpr int NFP  = NF + 16;// padded (quad prefetch overrun, zero-filled)
constexpr int EH   = 128;    // embedder hidden
constexpr int E    = 64;     // embedded dim
constexpr int H    = 64;     // lstm size
constexpr int SHD  = 256;    // shared hidden
constexpr int SD   = 128;    // shared dim
constexpr int NA   = 257;    // n_action
constexpr int NSHUF = 4;

__device__ __forceinline__ float fsig(float x) {
  return 1.f / (1.f + __expf(-x));
}
__device__ __forceinline__ float ftanh(float x) {
  return 1.f - 2.f / (__expf(2.f * x) + 1.f);
}

// ONE WAVE PER ROW, ZERO BARRIERS (r14+), quad-stream token loops (r18),
// vectorized COALESCED weight streams (r19). r20 lesson: transposed per-lane
// row dots break wave coalescing (64 strided lines vs 1 transaction) - the
// column layout is right; this round only DEEPENS ILP (4 independent load
// streams) in the gates/t1/sh/a1/v1 matvecs.
// Factored attention (r11+ verified): logits = h.(We2 qt) (const cancels);
// attended = (sum w h)@We2 + be2; h recomputed from We1 on the fly.
__global__ __launch_bounds__(64)
void seqnet(
    const float* __restrict__ state, const int* __restrict__ acquired,
    const float* __restrict__ We1, const float* __restrict__ be1,
    const float* __restrict__ We2, const float* __restrict__ be2,
    const float* __restrict__ Wih, const float* __restrict__ Whh,
    const float* __restrict__ bih, const float* __restrict__ bhh,
    const float* __restrict__ Ws1, const float* __restrict__ bs1,
    const float* __restrict__ Ws2, const float* __restrict__ bs2,
    const float* __restrict__ Wp1, const float* __restrict__ bp1,
    const float* __restrict__ Wp2, const float* __restrict__ bp2,
    const float* __restrict__ Wv1, const float* __restrict__ bv1,
    const float* __restrict__ Wv2, const float* __restrict__ bv2,
    float* __restrict__ out)
{
  const int row = blockIdx.x;
  const int l   = threadIdx.x;    // 0..63 (one wave)
  const int g   = l >> 4;         // token group 0..3
  const int sub = l & 15;         // k-slice owner within group
  const int kbase = sub * 8;      // owns k = kbase..kbase+7

  __shared__ int   id_s[NFP];
  __shared__ __align__(16) float val_s[NFP];
  __shared__ __align__(16) float w_s[NFP];
  __shared__ __align__(16) float rv_s[EH];
  __shared__ __align__(16) float u_s[EH];
  __shared__ __align__(16) float enc_s[EH];   // att[0:64] | qt[64:128]
  __shared__ __align__(16) float gates_s[256];
  __shared__ __align__(16) float t1_s[SHD];
  __shared__ __align__(16) float sh_s[SD];
  __shared__ __align__(16) float a1_s[SD];
  __shared__ __align__(16) float v1_s[SD];

  // ---------------- phase 0: closed-form "argsort" (wave-local) -----------
  const int* __restrict__ arow = acquired + row * NF;
  #pragma unroll
  for (int j = 0; j < 4; ++j) { id_s[l + 64 * j] = 0; val_s[l + 64 * j] = 0.f; }
  if (l < 16) { id_s[NF + l] = 0; val_s[NF + l] = 0.f; w_s[NF + l] = 0.f; }
  int aiv[4];
  unsigned long long m0, m1, m2, m3;
  aiv[0] = (arow[l]       != 0); m0 = __ballot(aiv[0]);
  aiv[1] = (arow[64 + l]  != 0); m1 = __ballot(aiv[1]);
  aiv[2] = (arow[128 + l] != 0); m2 = __ballot(aiv[2]);
  aiv[3] = (arow[192 + l] != 0); m3 = __ballot(aiv[3]);
  const int pc0 = __popcll(m0), pc1 = __popcll(m1);
  const int pc2 = __popcll(m2), pc3 = __popcll(m3);
  const int L = pc0 + pc1 + pc2 + pc3;
  {  // rank = # acquired with index > tok (descending stable order)
    const int suf1 = pc1 + pc2 + pc3, suf2 = pc2 + pc3, suf3 = pc3;
    if (aiv[0]) { const int r = (int)__popcll((m0 >> l) >> 1) + suf1;
      id_s[r] = l + 1;       val_s[r] = state[row * NF + l]; }
    if (aiv[1]) { const int r = (int)__popcll((m1 >> l) >> 1) + suf2;
      id_s[r] = 64 + l + 1;  val_s[r] = state[row * NF + 64 + l]; }
    if (aiv[2]) { const int r = (int)__popcll((m2 >> l) >> 1) + suf3;
      id_s[r] = 128 + l + 1; val_s[r] = state[row * NF + 128 + l]; }
    if (aiv[3]) { const int r = (int)__popcll((m3 >> l) >> 1);
      id_s[r] = 192 + l + 1; val_s[r] = state[row * NF + 192 + l]; }
  }

  float ct_r = 0.f;

  // hoisted per-lane h-recompute constants for k-slice [kbase, kbase+8)
  const float4 z0 = *(const float4*)(We1 + kbase);        // row 0 (val weight)
  const float4 z1 = *(const float4*)(We1 + kbase + 4);
  const float4 c0 = *(const float4*)(be1 + kbase);
  const float4 c1 = *(const float4*)(be1 + kbase + 4);

  if (L > 0) {
    const float invL = 1.f / (float)L;
    // group g owns tokens {4i+g}; quad = tokens 16j+g+{0,4,8,12}
    const int ntok  = (L > g) ? ((L - g + 3) >> 2) : 0;
    const int nquad = (ntok + 3) >> 2;
    for (int it = 0; it < NSHUF; ++it) {
      if (it == 0) {
        // qt == 0 -> uniform softmax over first L tokens
        #pragma unroll
        for (int j = 0; j < 4; ++j) w_s[l + 64 * j] = (l + 64 * j < L) ? invL : 0.f;
      } else {
        // rv = We2 @ qt : lane computes rv[l], rv[64+l]; qt from LDS float4
        {
          const float4* __restrict__ r0 = (const float4*)(We2 + l * E);
          const float4* __restrict__ r1 = (const float4*)(We2 + (64 + l) * E);
          float a0 = 0.f, a1 = 0.f, b0 = 0.f, b1 = 0.f;
          #pragma unroll
          for (int j = 0; j < 16; j += 2) {
            const float4 x0 = r0[j], x1 = r1[j];
            const float4 q4 = *(const float4*)(enc_s + 64 + 4 * j);
            a0 = fmaf(x0.x, q4.x, a0); a1 = fmaf(x1.x, q4.x, a1);
            a0 = fmaf(x0.y, q4.y, a0); a1 = fmaf(x1.y, q4.y, a1);
            a0 = fmaf(x0.z, q4.z, a0); a1 = fmaf(x1.z, q4.z, a1);
            a0 = fmaf(x0.w, q4.w, a0); a1 = fmaf(x1.w, q4.w, a1);
            const float4 y0 = r0[j + 1], y1 = r1[j + 1];
            const float4 q5 = *(const float4*)(enc_s + 64 + 4 * j + 4);
            b0 = fmaf(y0.x, q5.x, b0); b1 = fmaf(y1.x, q5.x, b1);
            b0 = fmaf(y0.y, q5.y, b0); b1 = fmaf(y1.y, q5.y, b1);
            b0 = fmaf(y0.z, q5.z, b0); b1 = fmaf(y1.z, q5.z, b1);
            b0 = fmaf(y0.w, q5.w, b0); b1 = fmaf(y1.w, q5.w, b1);
          }
          rv_s[l] = a0 + b0; rv_s[64 + l] = a1 + b1;
        }
        const float4 ra = *(const float4*)(rv_s + kbase);
        const float4 rb = *(const float4*)(rv_s + kbase + 4);
        // logits: quad-stream + 1-deep prefetch software pipeline
        float vcur[4]; float4 gA[4], gB[4];
        #pragma unroll
        for (int s = 0; s < 4; ++s) {
          const int tk = g + 4 * s;
          const int idt = id_s[tk]; vcur[s] = val_s[tk];
          gA[s] = *(const float4*)(We1 + idt * EH + kbase);
          gB[s] = *(const float4*)(We1 + idt * EH + kbase + 4);
        }
        for (int j = 0; j < nquad; ++j) {
          const int bnext = 16 * (j + 1) + g;
          float vnxt[4]; float4 gA2[4], gB2[4];
          #pragma unroll
          for (int s = 0; s < 4; ++s) {   // prefetch (pad-safe to NFP)
            const int tk = bnext + 4 * s;
            const int idt = id_s[tk]; vnxt[s] = val_s[tk];
            gA2[s] = *(const float4*)(We1 + idt * EH + kbase);
            gB2[s] = *(const float4*)(We1 + idt * EH + kbase + 4);
          }
          float p[4];
          #pragma unroll
          for (int s = 0; s < 4; ++s) {
            float h, pp;
            h = fmaxf(fmaf(vcur[s], z0.x, gA[s].x) + c0.x, 0.f); pp = h * ra.x;
            h = fmaxf(fmaf(vcur[s], z0.y, gA[s].y) + c0.y, 0.f); pp = fmaf(h, ra.y, pp);
            h = fmaxf(fmaf(vcur[s], z0.z, gA[s].z) + c0.z, 0.f); pp = fmaf(h, ra.z, pp);
            h = fmaxf(fmaf(vcur[s], z0.w, gA[s].w) + c0.w, 0.f); pp = fmaf(h, ra.w, pp);
            h = fmaxf(fmaf(vcur[s], z1.x, gB[s].x) + c1.x, 0.f); pp = fmaf(h, rb.x, pp);
            h = fmaxf(fmaf(vcur[s], z1.y, gB[s].y) + c1.y, 0.f); pp = fmaf(h, rb.y, pp);
            h = fmaxf(fmaf(vcur[s], z1.z, gB[s].z) + c1.z, 0.f); pp = fmaf(h, rb.z, pp);
            h = fmaxf(fmaf(vcur[s], z1.w, gB[s].w) + c1.w, 0.f); pp = fmaf(h, rb.w, pp);
            p[s] = pp;
          }
          #pragma unroll
          for (int s = 0; s < 4; ++s) {
            p[s] += __shfl_xor(p[s], 1); p[s] += __shfl_xor(p[s], 2);
            p[s] += __shfl_xor(p[s], 4); p[s] += __shfl_xor(p[s], 8);
          }
          if (sub == 0) {
            const int bcur = 16 * j + g;
            w_s[bcur]      = p[0]; w_s[bcur + 4]  = p[1];
            w_s[bcur + 8]  = p[2]; w_s[bcur + 12] = p[3];
          }
          #pragma unroll
          for (int s = 0; s < 4; ++s) { vcur[s] = vnxt[s]; gA[s] = gA2[s]; gB[s] = gB2[s]; }
        }
        // softmax over w_s[0..L), 4 tokens per lane
        float x0 = (l < L)       ? w_s[l]       : -1e30f;
        float x1 = (64 + l < L)  ? w_s[64 + l]  : -1e30f;
        float x2 = (128 + l < L) ? w_s[128 + l] : -1e30f;
        float x3 = (192 + l < L) ? w_s[192 + l] : -1e30f;
        float mx = fmaxf(fmaxf(x0, x1), fmaxf(x2, x3));
        #pragma unroll
        for (int d = 32; d > 0; d >>= 1) mx = fmaxf(mx, __shfl_xor(mx, d));
        const float e0 = (l < L)       ? __expf(x0 - mx) : 0.f;
        const float e1 = (64 + l < L)  ? __expf(x1 - mx) : 0.f;
        const float e2 = (128 + l < L) ? __expf(x2 - mx) : 0.f;
        const float e3 = (192 + l < L) ? __expf(x3 - mx) : 0.f;
        float s = (e0 + e1) + (e2 + e3);
        #pragma unroll
        for (int d = 32; d > 0; d >>= 1) s += __shfl_xor(s, d);
        const float inv = 1.f / s;
        w_s[l]       = e0 * inv;
        w_s[64 + l]  = e1 * inv;
        w_s[128 + l] = e2 * inv;
        w_s[192 + l] = e3 * inv;
      }

      // u[k] = sum_tok w*h : quad-stream + 1-deep prefetch pipeline
      float4 ua{0, 0, 0, 0}, ub{0, 0, 0, 0};
      {
        float vcur[4], wcur[4]; float4 gA[4], gB[4];
        #pragma unroll
        for (int s = 0; s < 4; ++s) {
          const int tk = g + 4 * s;
          const int idt = id_s[tk]; vcur[s] = val_s[tk]; wcur[s] = w_s[tk];
          gA[s] = *(const float4*)(We1 + idt * EH + kbase);
          gB[s] = *(const float4*)(We1 + idt * EH + kbase + 4);
        }
        for (int j = 0; j < nquad; ++j) {
          const int bnext = 16 * (j + 1) + g;
          float vnxt[4], wnxt[4]; float4 gA2[4], gB2[4];
          #pragma unroll
          for (int s = 0; s < 4; ++s) {   // prefetch (pad-safe; w=0 beyond L)
            const int tk = bnext + 4 * s;
            const int idt = id_s[tk]; vnxt[s] = val_s[tk]; wnxt[s] = w_s[tk];
            gA2[s] = *(const float4*)(We1 + idt * EH + kbase);
            gB2[s] = *(const float4*)(We1 + idt * EH + kbase + 4);
          }
          #pragma unroll
          for (int s = 0; s < 4; ++s) {
            const float vt = vcur[s], wt = wcur[s];
            float h;
            h = fmaxf(fmaf(vt, z0.x, gA[s].x) + c0.x, 0.f); ua.x = fmaf(wt, h, ua.x);
            h = fmaxf(fmaf(vt, z0.y, gA[s].y) + c0.y, 0.f); ua.y = fmaf(wt, h, ua.y);
            h = fmaxf(fmaf(vt, z0.z, gA[s].z) + c0.z, 0.f); ua.z = fmaf(wt, h, ua.z);
            h = fmaxf(fmaf(vt, z0.w, gA[s].w) + c0.w, 0.f); ua.w = fmaf(wt, h, ua.w);
            h = fmaxf(fmaf(vt, z1.x, gB[s].x) + c1.x, 0.f); ub.x = fmaf(wt, h, ub.x);
            h = fmaxf(fmaf(vt, z1.y, gB[s].y) + c1.y, 0.f); ub.y = fmaf(wt, h, ub.y);
            h = fmaxf(fmaf(vt, z1.z, gB[s].z) + c1.z, 0.f); ub.z = fmaf(wt, h, ub.z);
            h = fmaxf(fmaf(vt, z1.w, gB[s].w) + c1.w, 0.f); ub.w = fmaf(wt, h, ub.w);
          }
          #pragma unroll
          for (int s = 0; s < 4; ++s) {
            vcur[s] = vnxt[s]; wcur[s] = wnxt[s]; gA[s] = gA2[s]; gB[s] = gB2[s];
          }
        }
      }
      #pragma unroll
      for (int d = 16; d <= 32; d <<= 1) {   // cross-group: same sub = same k
        ua.x += __shfl_xor(ua.x, d); ua.y += __shfl_xor(ua.y, d);
        ua.z += __shfl_xor(ua.z, d); ua.w += __shfl_xor(ua.w, d);
        ub.x += __shfl_xor(ub.x, d); ub.y += __shfl_xor(ub.y, d);
        ub.z += __shfl_xor(ub.z, d); ub.w += __shfl_xor(ub.w, d);
      }
      if (l < 16) {
        *(float4*)(u_s + l * 8)     = ua;
        *(float4*)(u_s + l * 8 + 4) = ub;
      }

      // attended[l] = sum_k u[k]*We2[k][l] + be2[l]   (coalesced columns)
      {
        float a0 = 0.f, a1 = 0.f, a2 = 0.f, a3 = 0.f;
        #pragma unroll 4
        for (int k = 0; k < EH; k += 4) {
          a0 = fmaf(u_s[k],     We2[(k)     * E + l], a0);
          a1 = fmaf(u_s[k + 1], We2[(k + 1) * E + l], a1);
          a2 = fmaf(u_s[k + 2], We2[(k + 2) * E + l], a2);
          a3 = fmaf(u_s[k + 3], We2[(k + 3) * E + l], a3);
        }
        enc_s[l] = (a0 + a1) + (a2 + a3) + be2[l];
      }

      // gates: lane owns cols 4l..4l+3; 4 independent float4 load streams
      {
        float4 acc0{0,0,0,0}, acc1{0,0,0,0}, acc2{0,0,0,0}, acc3{0,0,0,0};
        #pragma unroll 2
        for (int e = 0; e < E; e += 4) {
          const float av0 = enc_s[e],     av1 = enc_s[e + 1];
          const float av2 = enc_s[e + 2], av3 = enc_s[e + 3];
          const float4 w0 = *(const float4*)(Wih + (e)     * 256 + 4 * l);
          const float4 w1 = *(const float4*)(Wih + (e + 1) * 256 + 4 * l);
          const float4 w2 = *(const float4*)(Wih + (e + 2) * 256 + 4 * l);
          const float4 w3 = *(const float4*)(Wih + (e + 3) * 256 + 4 * l);
          acc0.x = fmaf(av0, w0.x, acc0.x); acc0.y = fmaf(av0, w0.y, acc0.y);
          acc0.z = fmaf(av0, w0.z, acc0.z); acc0.w = fmaf(av0, w0.w, acc0.w);
          acc1.x = fmaf(av1, w1.x, acc1.x); acc1.y = fmaf(av1, w1.y, acc1.y);
          acc1.z = fmaf(av1, w1.z, acc1.z); acc1.w = fmaf(av1, w1.w, acc1.w);
          acc2.x = fmaf(av2, w2.x, acc2.x); acc2.y = fmaf(av2, w2.y, acc2.y);
          acc2.z = fmaf(av2, w2.z, acc2.z); acc2.w = fmaf(av2, w2.w, acc2.w);
          acc3.x = fmaf(av3, w3.x, acc3.x); acc3.y = fmaf(av3, w3.y, acc3.y);
          acc3.z = fmaf(av3, w3.z, acc3.z); acc3.w = fmaf(av3, w3.w, acc3.w);
        }
        if (it > 0) {
          #pragma unroll 2
          for (int e = 0; e < E; e += 4) {
            const float qv0 = enc_s[64 + e],     qv1 = enc_s[64 + e + 1];
            const float qv2 = enc_s[64 + e + 2], qv3 = enc_s[64 + e + 3];
            const float4 w0 = *(const float4*)(Whh + (e)     * 256 + 4 * l);
            const float4 w1 = *(const float4*)(Whh + (e + 1) * 256 + 4 * l);
            const float4 w2 = *(const float4*)(Whh + (e + 2) * 256 + 4 * l);
            const float4 w3 = *(const float4*)(Whh + (e + 3) * 256 + 4 * l);
            acc0.x = fmaf(qv0, w0.x, acc0.x); acc0.y = fmaf(qv0, w0.y, acc0.y);
            acc0.z = fmaf(qv0, w0.z, acc0.z); acc0.w = fmaf(qv0, w0.w, acc0.w);
            acc1.x = fmaf(qv1, w1.x, acc1.x); acc1.y = fmaf(qv1, w1.y, acc1.y);
            acc1.z = fmaf(qv1, w1.z, acc1.z); acc1.w = fmaf(qv1, w1.w, acc1.w);
            acc2.x = fmaf(qv2, w2.x, acc2.x); acc2.y = fmaf(qv2, w2.y, acc2.y);
            acc2.z = fmaf(qv2, w2.z, acc2.z); acc2.w = fmaf(qv2, w2.w, acc2.w);
            acc3.x = fmaf(qv3, w3.x, acc3.x); acc3.y = fmaf(qv3, w3.y, acc3.y);
            acc3.z = fmaf(qv3, w3.z, acc3.z); acc3.w = fmaf(qv3, w3.w, acc3.w);
          }
        }
        const float4 bi = *(const float4*)(bih + 4 * l);
        const float4 bh = *(const float4*)(bhh + 4 * l);
        float4 gacc;
        gacc.x = (acc0.x + acc1.x) + (acc2.x + acc3.x) + bi.x + bh.x;
        gacc.y = (acc0.y + acc1.y) + (acc2.y + acc3.y) + bi.y + bh.y;
        gacc.z = (acc0.z + acc1.z) + (acc2.z + acc3.z) + bi.z + bh.z;
        gacc.w = (acc0.w + acc1.w) + (acc2.w + acc3.w) + bi.w + bh.w;
        *(float4*)(gates_s + 4 * l) = gacc;
        // per-cell gates back from LDS (same-wave RAW, ordered)
        const float gi = gates_s[l];
        const float gf = gates_s[64 + l];
        const float gg = gates_s[128 + l];
        const float go = gates_s[192 + l];
        ct_r = fsig(gf) * ct_r + fsig(gi) * ftanh(gg);
        enc_s[64 + l] = fsig(go) * ftanh(ct_r);   // qt in LDS (wave-local)
      }
    }
  } else {
    enc_s[l] = 0.f; enc_s[64 + l] = 0.f;   // reference zeroes encoded
  }

  // ---------------- phase 3: DuelingNet (4-stream coalesced matvecs) ------
  {  // t1 cols 4l..4l+3 via float4; 4 independent load streams
    float4 acc0{0,0,0,0}, acc1{0,0,0,0}, acc2{0,0,0,0}, acc3{0,0,0,0};
    #pragma unroll 2
    for (int k = 0; k < EH; k += 4) {
      const float e0 = enc_s[k],     e1 = enc_s[k + 1];
      const float e2 = enc_s[k + 2], e3 = enc_s[k + 3];
      const float4 w0 = *(const float4*)(Ws1 + (k)     * SHD + 4 * l);
      const float4 w1 = *(const float4*)(Ws1 + (k + 1) * SHD + 4 * l);
      const float4 w2 = *(const float4*)(Ws1 + (k + 2) * SHD + 4 * l);
      const float4 w3 = *(const float4*)(Ws1 + (k + 3) * SHD + 4 * l);
      acc0.x = fmaf(e0, w0.x, acc0.x); acc0.y = fmaf(e0, w0.y, acc0.y);
      acc0.z = fmaf(e0, w0.z, acc0.z); acc0.w = fmaf(e0, w0.w, acc0.w);
      acc1.x = fmaf(e1, w1.x, acc1.x); acc1.y = fmaf(e1, w1.y, acc1.y);
      acc1.z = fmaf(e1, w1.z, acc1.z); acc1.w = fmaf(e1, w1.w, acc1.w);
      acc2.x = fmaf(e2, w2.x, acc2.x); acc2.y = fmaf(e2, w2.y, acc2.y);
      acc2.z = fmaf(e2, w2.z, acc2.z); acc2.w = fmaf(e2, w2.w, acc2.w);
      acc3.x = fmaf(e3, w3.x, acc3.x); acc3.y = fmaf(e3, w3.y, acc3.y);
      acc3.z = fmaf(e3, w3.z, acc3.z); acc3.w = fmaf(e3, w3.w, acc3.w);
    }
    const float4 b4 = *(const float4*)(bs1 + 4 * l);
    t1_s[4 * l]     = fmaxf((acc0.x + acc1.x) + (acc2.x + acc3.x) + b4.x, 0.f);
    t1_s[4 * l + 1] = fmaxf((acc0.y + acc1.y) + (acc2.y + acc3.y) + b4.y, 0.f);
    t1_s[4 * l + 2] = fmaxf((acc0.z + acc1.z) + (acc2.z + acc3.z) + b4.z, 0.f);
    t1_s[4 * l + 3] = fmaxf((acc0.w + acc1.w) + (acc2.w + acc3.w) + b4.w, 0.f);
  }
  {  // sh cols 2l, 2l+1 via float2; 4 independent load streams
    float2 acc0{0,0}, acc1{0,0}, acc2{0,0}, acc3{0,0};
    #pragma unroll 2
    for (int k = 0; k < SHD; k += 4) {
      const float t0 = t1_s[k],     t1v = t1_s[k + 1];
      const float t2 = t1_s[k + 2], t3v = t1_s[k + 3];
      const float2 w0 = *(const float2*)(Ws2 + (k)     * SD + 2 * l);
      const float2 w1 = *(const float2*)(Ws2 + (k + 1) * SD + 2 * l);
      const float2 w2 = *(const float2*)(Ws2 + (k + 2) * SD + 2 * l);
      const float2 w3 = *(const float2*)(Ws2 + (k + 3) * SD + 2 * l);
      acc0.x = fmaf(t0, w0.x, acc0.x); acc0.y = fmaf(t0, w0.y, acc0.y);
      acc1.x = fmaf(t1v, w1.x, acc1.x); acc1.y = fmaf(t1v, w1.y, acc1.y);
      acc2.x = fmaf(t2, w2.x, acc2.x); acc2.y = fmaf(t2, w2.y, acc2.y);
      acc3.x = fmaf(t3v, w3.x, acc3.x); acc3.y = fmaf(t3v, w3.y, acc3.y);
    }
    sh_s[2 * l]     = fmaxf((acc0.x + acc1.x) + (acc2.x + acc3.x) + bs2[2 * l],     0.f);
    sh_s[2 * l + 1] = fmaxf((acc0.y + acc1.y) + (acc2.y + acc3.y) + bs2[2 * l + 1], 0.f);
  }
  {  // a1, v1 cols 2l, 2l+1 via float2; 4 streams (2 per net)
    float2 pa0{0,0}, pa1{0,0}, qa0{0,0}, qa1{0,0};
    #pragma unroll 2
    for (int k = 0; k < SD; k += 2) {
      const float s0 = sh_s[k], s1 = sh_s[k + 1];
      const float2 wp0 = *(const float2*)(Wp1 + (k)     * SD + 2 * l);
      const float2 wp1 = *(const float2*)(Wp1 + (k + 1) * SD + 2 * l);
      const float2 wv0 = *(const float2*)(Wv1 + (k)     * SD + 2 * l);
      const float2 wv1 = *(const float2*)(Wv1 + (k + 1) * SD + 2 * l);
      pa0.x = fmaf(s0, wp0.x, pa0.x); pa0.y = fmaf(s0, wp0.y, pa0.y);
      pa1.x = fmaf(s1, wp1.x, pa1.x); pa1.y = fmaf(s1, wp1.y, pa1.y);
      qa0.x = fmaf(s0, wv0.x, qa0.x); qa0.y = fmaf(s0, wv0.y, qa0.y);
      qa1.x = fmaf(s1, wv1.x, qa1.x); qa1.y = fmaf(s1, wv1.y, qa1.y);
    }
    a1_s[2 * l]     = fmaxf(pa0.x + pa1.x + bp1[2 * l],     0.f);
    a1_s[2 * l + 1] = fmaxf(pa0.y + pa1.y + bp1[2 * l + 1], 0.f);
    v1_s[2 * l]     = fmaxf(qa0.x + qa1.x + bv1[2 * l],     0.f);
    v1_s[2 * l + 1] = fmaxf(qa0.y + qa1.y + bv1[2 * l + 1], 0.f);
  }
  // adv cols l+64j (4 per lane; Wp2 row stride 257 -> keep coalesced dword)
  float a0 = 0.f, a1 = 0.f, a2 = 0.f, a3 = 0.f;
  #pragma unroll 2
  for (int k = 0; k < SD; ++k) {
    const float av = a1_s[k];
    const float* __restrict__ wr = Wp2 + k * NA;
    a0 = fmaf(av, wr[l],       a0);
    a1 = fmaf(av, wr[64 + l],  a1);
    a2 = fmaf(av, wr[128 + l], a2);
    a3 = fmaf(av, wr[192 + l], a3);
  }
  a0 += bp2[l]; a1 += bp2[64 + l]; a2 += bp2[128 + l]; a3 += bp2[192 + l];
  // adv col 256: distributed dot (2 k per lane) + butterfly
  float c4 = fmaf(a1_s[2 * l], Wp2[(2 * l) * NA + 256],
                  a1_s[2 * l + 1] * Wp2[(2 * l + 1) * NA + 256]);
  #pragma unroll
  for (int d = 32; d > 0; d >>= 1) c4 += __shfl_xor(c4, d);
  const float adv4 = c4 + bp2[256];
  // v scalar
  float vv = fmaf(v1_s[l], Wv2[l], v1_s[64 + l] * Wv2[64 + l]);
  #pragma unroll
  for (int d = 32; d > 0; d >>= 1) vv += __shfl_xor(vv, d);
  const float v = vv + bv2[0];
  // mean over 257 cols
  float ss = (a0 + a1) + (a2 + a3);
  #pragma unroll
  for (int d = 32; d > 0; d >>= 1) ss += __shfl_xor(ss, d);
  const float mean = (ss + adv4) * (1.f / (float)NA);

  const float base = v - mean;
  float* __restrict__ orow = out + row * NA;
  orow[l]       = base + a0;
  orow[64 + l]  = base + a1;
  orow[128 + l] = base + a2;
  orow[192 + l] = base + a3;
  if (l == 0) orow[256] = base + adv4;
}

}  // namespace

extern "C" void kernel_launch(void* const* d_in, const int* in_sizes, int n_in,
                              void* d_out, int out_size, void* d_ws, size_t ws_size,
                              hipStream_t stream) {
  const float* state    = (const float*)d_in[0];
  const int*   acquired = (const int*)d_in[1];
  const float* We1 = (const float*)d_in[2];
  const float* be1 = (const float*)d_in[3];
  const float* We2 = (const float*)d_in[4];
  const float* be2 = (const float*)d_in[5];
  const float* Wih = (const float*)d_in[6];
  const float* Whh = (const float*)d_in[7];
  const float* bih = (const float*)d_in[8];
  const float* bhh = (const float*)d_in[9];
  const float* Ws1 = (const float*)d_in[10];
  const float* bs1 = (const float*)d_in[11];
  const float* Ws2 = (const float*)d_in[12];
  const float* bs2 = (const float*)d_in[13];
  const float* Wp1 = (const float*)d_in[14];
  const float* bp1 = (const float*)d_in[15];
  const float* Wp2 = (const float*)d_in[16];
  const float* bp2 = (const float*)d_in[17];
  const float* Wv1 = (const float*)d_in[18];
  const float* bv1 = (const float*)d_in[19];
  const float* Wv2 = (const float*)d_in[20];
  const float* bv2 = (const float*)d_in[21];
  float* out = (float*)d_out;

  const int Bn = in_sizes[0] / NF;   // 2048 rows; one 64-thread wave per row
  hipLaunchKernelGGL(seqnet, dim3(Bn), dim3(64), 0, stream,
                     state, acquired, We1, be1, We2, be2, Wih, Whh, bih, bhh,
                     Ws1, bs1, Ws2, bs2, Wp1, bp1, Wp2, bp2, Wv1, bv1, Wv2, bv2,
                     out);
}